// Round 1
// 646.614 us; speedup vs baseline: 1.0004x; 1.0004x over previous
//
#include <hip/hip_runtime.h>
#include <cstdint>
#include <cstddef>

#define B_ROWS 65536
#define OUT_N  2048
#define IN_K   64
#define LOG2E  1.4426950408889634f

typedef __attribute__((ext_vector_type(8))) short bf16x8;
typedef __attribute__((ext_vector_type(4))) float f32x4;
typedef __attribute__((ext_vector_type(4))) short s16x4;

__device__ __forceinline__ unsigned short f2bf_rtn(float v) {
  unsigned u = __float_as_uint(v);
  u += 0x7fffu + ((u >> 16) & 1u);
  return (unsigned short)(u >> 16);
}
__device__ __forceinline__ float bf2f(unsigned short s) {
  return __uint_as_float(((unsigned)s) << 16);
}

// Precompute: centers -> bf16 hi/lo split, c2 = sum(c^2), iv = exp(-2*ls)*log2e
__global__ __launch_bounds__(64) void rbf_pre(
    const float* __restrict__ centers, const float* __restrict__ log_sigmas,
    unsigned short* __restrict__ ch, unsigned short* __restrict__ cl,
    float* __restrict__ c2, float* __restrict__ iv) {
  const int o = blockIdx.x;
  const int lane = threadIdx.x;
  float v = centers[o * IN_K + lane];
  unsigned short h = f2bf_rtn(v);
  float hf = bf2f(h);
  unsigned short l = f2bf_rtn(v - hf);
  ch[o * IN_K + lane] = h;
  cl[o * IN_K + lane] = l;
  float s = v * v;
  #pragma unroll
  for (int off = 32; off > 0; off >>= 1) s += __shfl_down(s, off, 64);
  if (lane == 0) {
    c2[o] = s;
    float ls = log_sigmas[o];
    iv[o] = __builtin_amdgcn_exp2f(-2.0f * ls * LOG2E) * LOG2E;
  }
}

// Main: each block owns 64 rows of x, sweeps all 2048 centers.
// MFMA roles: A = centers tile (m = o), B = x tile (n = b).
// C/D layout (gfx950 16x16x32): col = lane&15 -> b ; row = quad*4+reg -> o
// => each lane stores 4 consecutive o's as one dwordx4.
//
// Round-1 change: the x-tile B-fragments are invariant across the entire
// oc loop, so hoist ALL of them (16 x bf16x8 = 64 VGPRs) + x2 + row
// pointers into registers ONCE. Steady-state loop has ZERO LDS ops:
// ds_read_b128 count drops 512 -> 16 per thread, and the per-nt
// lgkmcnt stall before the MFMA chain disappears.
// __launch_bounds__(256,3) keeps occupancy >= 3 waves/SIMD (12/CU).
__global__ __launch_bounds__(256, 3) void rbf_main(
    const float* __restrict__ x,
    const unsigned short* __restrict__ ch, const unsigned short* __restrict__ cl,
    const float* __restrict__ c2, const float* __restrict__ iv,
    float* __restrict__ out) {
  // 72-short row pitch (+16B) breaks the 128B power-of-2 stride -> only 2-way
  // bank aliasing on ds_read_b128, which is free on CDNA4.
  __shared__ unsigned short xh[64 * 72];
  __shared__ unsigned short xl[64 * 72];
  __shared__ float x2s[64];

  const int t = threadIdx.x;
  const int b0 = blockIdx.x * 64;

  if (t < 64) x2s[t] = 0.0f;
  __syncthreads();

  // Stage x tile: 64 rows x 64 cols fp32 = 1024 float4, 4 per thread (coalesced)
  const f32x4* xv = (const f32x4*)(x + (size_t)b0 * IN_K);
  #pragma unroll
  for (int i = 0; i < 4; ++i) {
    int f4 = i * 256 + t;            // 0..1023
    f32x4 v = xv[f4];
    int row = f4 >> 4;               // 16 float4 per row
    int col = (f4 & 15) * 4;
    s16x4 h, l;
    #pragma unroll
    for (int j = 0; j < 4; ++j) {
      unsigned short hh = f2bf_rtn(v[j]);
      h[j] = (short)hh;
      l[j] = (short)f2bf_rtn(v[j] - bf2f(hh));
    }
    *(s16x4*)(xh + row * 72 + col) = h;
    *(s16x4*)(xl + row * 72 + col) = l;
    atomicAdd(&x2s[row], v[0] * v[0] + v[1] * v[1] + v[2] * v[2] + v[3] * v[3]);
  }
  __syncthreads();

  const int lane = t & 63;
  const int w    = t >> 6;        // wave id 0..3
  const int n    = lane & 15;     // free-index for both A and B operands
  const int quad = lane >> 4;
  const int kq   = quad * 8;      // k-offset within 32-chunk

  // ---- one-time hoist of the whole x-tile fragment set (oc-invariant) ----
  bf16x8 BH0[4], BH1[4], BL0[4], BL1[4];   // 64 VGPRs
  float  X2[4];
  float* prow[4];
  #pragma unroll
  for (int nt = 0; nt < 4; ++nt) {
    const int brow = nt * 16 + n;
    const unsigned short* bp  = xh + brow * 72 + kq;
    const unsigned short* bpl = xl + brow * 72 + kq;
    BH0[nt] = *(const bf16x8*)(bp);
    BH1[nt] = *(const bf16x8*)(bp + 32);
    BL0[nt] = *(const bf16x8*)(bpl);
    BL1[nt] = *(const bf16x8*)(bpl + 32);
    X2[nt]  = x2s[brow];
    prow[nt] = out + (size_t)(b0 + brow) * OUT_N + quad * 4;
  }

  for (int oc = 0; oc < OUT_N; oc += 256) {
    const int obase = oc + w * 64;          // each wave owns 64 consecutive o
    #pragma unroll
    for (int mt = 0; mt < 4; ++mt) {
      const int o0 = obase + mt * 16;
      const int arow = o0 + n;
      // A-frags: centers rows (hi and lo), K halves 0..31 / 32..63 (L2-hit)
      bf16x8 ah0 = *(const bf16x8*)(ch + arow * IN_K + kq);
      bf16x8 ah1 = *(const bf16x8*)(ch + arow * IN_K + kq + 32);
      bf16x8 al0 = *(const bf16x8*)(cl + arow * IN_K + kq);
      bf16x8 al1 = *(const bf16x8*)(cl + arow * IN_K + kq + 32);
      f32x4 c2v = *(const f32x4*)(c2 + o0 + quad * 4);
      f32x4 ivv = *(const f32x4*)(iv + o0 + quad * 4);
      #pragma unroll
      for (int nt = 0; nt < 4; ++nt) {
        f32x4 acc = {0.0f, 0.0f, 0.0f, 0.0f};
        // 3-pass split-precision dot: hh + h*l + l*h (l*l ~2^-16 rel, dropped)
        acc = __builtin_amdgcn_mfma_f32_16x16x32_bf16(ah0, BH0[nt], acc, 0, 0, 0);
        acc = __builtin_amdgcn_mfma_f32_16x16x32_bf16(ah1, BH1[nt], acc, 0, 0, 0);
        acc = __builtin_amdgcn_mfma_f32_16x16x32_bf16(ah0, BL0[nt], acc, 0, 0, 0);
        acc = __builtin_amdgcn_mfma_f32_16x16x32_bf16(ah1, BL1[nt], acc, 0, 0, 0);
        acc = __builtin_amdgcn_mfma_f32_16x16x32_bf16(al0, BH0[nt], acc, 0, 0, 0);
        acc = __builtin_amdgcn_mfma_f32_16x16x32_bf16(al1, BH1[nt], acc, 0, 0, 0);
        const float x2v = X2[nt];
        f32x4 r;
        #pragma unroll
        for (int j = 0; j < 4; ++j) {
          float sq = x2v - 2.0f * acc[j] + c2v[j];
          sq = fmaxf(sq, 0.0f);                      // match ref clamp
          r[j] = __builtin_amdgcn_exp2f(-sq * ivv[j]);
        }
        *(f32x4*)(prow[nt] + o0) = r;
      }
    }
  }
}

extern "C" void kernel_launch(void* const* d_in, const int* in_sizes, int n_in,
                              void* d_out, int out_size, void* d_ws, size_t ws_size,
                              hipStream_t stream) {
  (void)in_sizes; (void)n_in; (void)out_size; (void)ws_size;
  const float* x       = (const float*)d_in[0];
  const float* centers = (const float*)d_in[1];
  const float* ls      = (const float*)d_in[2];
  float* out = (float*)d_out;

  // ws layout: c_hi (256KB) | c_lo (256KB) | c2 (8KB) | inv2 (8KB)  = 528KB
  char* ws = (char*)d_ws;
  unsigned short* ch = (unsigned short*)(ws);
  unsigned short* cl = (unsigned short*)(ws + 262144);
  float* c2 = (float*)(ws + 524288);
  float* iv = (float*)(ws + 532480);

  rbf_pre<<<OUT_N, 64, 0, stream>>>(centers, ls, ch, cl, c2, iv);
  rbf_main<<<B_ROWS / 64, 256, 0, stream>>>(x, ch, cl, c2, iv, out);
}

// Round 2
// 580.024 us; speedup vs baseline: 1.1153x; 1.1148x over previous
//
#include <hip/hip_runtime.h>
#include <cstdint>
#include <cstddef>

#define B_ROWS 65536
#define OUT_N  2048
#define IN_K   64
#define LOG2E  1.4426950408889634f

#define ROWS_B 256   // x-rows per block
#define OC_B   256   // centers per block (64 per wave)

typedef __attribute__((ext_vector_type(8))) short bf16x8;
typedef __attribute__((ext_vector_type(4))) float f32x4;
typedef __attribute__((ext_vector_type(4))) short s16x4;

__device__ __forceinline__ unsigned short f2bf_rtn(float v) {
  unsigned u = __float_as_uint(v);
  u += 0x7fffu + ((u >> 16) & 1u);
  return (unsigned short)(u >> 16);
}
__device__ __forceinline__ float bf2f(unsigned short s) {
  return __uint_as_float(((unsigned)s) << 16);
}

// Precompute: centers -> bf16 hi/lo split, c2 = sum(c^2), iv = exp(-2*ls)*log2e
__global__ __launch_bounds__(64) void rbf_pre(
    const float* __restrict__ centers, const float* __restrict__ log_sigmas,
    unsigned short* __restrict__ ch, unsigned short* __restrict__ cl,
    float* __restrict__ c2, float* __restrict__ iv) {
  const int o = blockIdx.x;
  const int lane = threadIdx.x;
  float v = centers[o * IN_K + lane];
  unsigned short h = f2bf_rtn(v);
  float hf = bf2f(h);
  unsigned short l = f2bf_rtn(v - hf);
  ch[o * IN_K + lane] = h;
  cl[o * IN_K + lane] = l;
  float s = v * v;
  #pragma unroll
  for (int off = 32; off > 0; off >>= 1) s += __shfl_down(s, off, 64);
  if (lane == 0) {
    c2[o] = s;
    float ls = log_sigmas[o];
    iv[o] = __builtin_amdgcn_exp2f(-2.0f * ls * LOG2E) * LOG2E;
  }
}

// Round-2 restructure: 2D tiling, 256 rows x 256 centers per block.
// Each wave owns 64 centers -> its FULL A-fragment set (16 x bf16x8) plus
// c2/iv (8 x f32x4) fits in registers, loaded ONCE per block. The steady
// state has ZERO global loads: only ds_read (lgkmcnt) + MFMA + VALU +
// fire-and-forget stores. Rationale: vmcnt is a single FIFO counting loads
// AND stores, so the old per-mt A-load waits forced the wave to drain its
// in-flight stores 32x per block -> shallow store queue -> ~2.5 TB/s write
// BW. With no vmcnt waits in the loop the store stream behaves like the
// fill kernel (78% of peak at low occupancy).
// MFMA roles: A = centers (m = o), B = x rows (n = b).
// C/D layout (gfx950 16x16x32): col = lane&15 -> b ; row = quad*4+reg -> o.
__global__ __launch_bounds__(256, 2) void rbf_main(
    const float* __restrict__ x,
    const unsigned short* __restrict__ ch, const unsigned short* __restrict__ cl,
    const float* __restrict__ c2, const float* __restrict__ iv,
    float* __restrict__ out) {
  // 72-short row pitch (+16B) breaks the 128B power-of-2 stride -> only 2-way
  // bank aliasing on ds_read_b128, which is free on CDNA4. (Measured 0
  // SQ_LDS_BANK_CONFLICT at this pitch.)
  __shared__ unsigned short xh[ROWS_B * 72];
  __shared__ unsigned short xl[ROWS_B * 72];
  __shared__ float x2s[ROWS_B];

  const int t = threadIdx.x;
  const int b0  = blockIdx.x * ROWS_B;
  const int ocb = blockIdx.y * OC_B;

  x2s[t] = 0.0f;                      // 256 threads cover all 256 rows
  __syncthreads();

  // Stage x tile: 256 rows x 64 cols fp32 = 4096 float4, 16 per thread
  const f32x4* xv = (const f32x4*)(x + (size_t)b0 * IN_K);
  #pragma unroll
  for (int i = 0; i < 16; ++i) {
    int f4 = i * 256 + t;            // 0..4095
    f32x4 v = xv[f4];
    int row = f4 >> 4;               // 16 float4 per row
    int col = (f4 & 15) * 4;
    s16x4 h, l;
    #pragma unroll
    for (int j = 0; j < 4; ++j) {
      unsigned short hh = f2bf_rtn(v[j]);
      h[j] = (short)hh;
      l[j] = (short)f2bf_rtn(v[j] - bf2f(hh));
    }
    *(s16x4*)(xh + row * 72 + col) = h;
    *(s16x4*)(xl + row * 72 + col) = l;
    atomicAdd(&x2s[row], v[0] * v[0] + v[1] * v[1] + v[2] * v[2] + v[3] * v[3]);
  }
  __syncthreads();

  const int lane = t & 63;
  const int w    = t >> 6;        // wave id 0..3 -> owns 64 consecutive o
  const int n    = lane & 15;     // free-index for both A and B operands
  const int quad = lane >> 4;
  const int kq   = quad * 8;      // k-offset within 32-chunk

  const int obase = ocb + w * 64;

  // ---- one-time hoist of the wave's ENTIRE center set into registers ----
  bf16x8 AH0[4], AH1[4], AL0[4], AL1[4];   // 64 VGPRs
  f32x4  C2[4], IV[4];                     // 32 VGPRs
  #pragma unroll
  for (int mt = 0; mt < 4; ++mt) {
    const int arow = obase + mt * 16 + n;
    AH0[mt] = *(const bf16x8*)(ch + arow * IN_K + kq);
    AH1[mt] = *(const bf16x8*)(ch + arow * IN_K + kq + 32);
    AL0[mt] = *(const bf16x8*)(cl + arow * IN_K + kq);
    AL1[mt] = *(const bf16x8*)(cl + arow * IN_K + kq + 32);
    C2[mt]  = *(const f32x4*)(c2 + obase + mt * 16 + quad * 4);
    IV[mt]  = *(const f32x4*)(iv + obase + mt * 16 + quad * 4);
  }

  // ---- steady state: no global loads, stores never waited on ----
  #pragma unroll 2
  for (int nt = 0; nt < 16; ++nt) {
    const int brow = nt * 16 + n;
    const unsigned short* bp  = xh + brow * 72 + kq;
    const unsigned short* bpl = xl + brow * 72 + kq;
    bf16x8 bh0 = *(const bf16x8*)(bp);
    bf16x8 bh1 = *(const bf16x8*)(bp + 32);
    bf16x8 bl0 = *(const bf16x8*)(bpl);
    bf16x8 bl1 = *(const bf16x8*)(bpl + 32);
    const float x2v = x2s[brow];
    float* prow = out + (size_t)(b0 + brow) * OUT_N + obase + quad * 4;
    #pragma unroll
    for (int mt = 0; mt < 4; ++mt) {
      f32x4 acc = {0.0f, 0.0f, 0.0f, 0.0f};
      // 3-pass split-precision dot: hh + h*l + l*h (l*l ~2^-16 rel, dropped)
      acc = __builtin_amdgcn_mfma_f32_16x16x32_bf16(AH0[mt], bh0, acc, 0, 0, 0);
      acc = __builtin_amdgcn_mfma_f32_16x16x32_bf16(AH1[mt], bh1, acc, 0, 0, 0);
      acc = __builtin_amdgcn_mfma_f32_16x16x32_bf16(AH0[mt], bl0, acc, 0, 0, 0);
      acc = __builtin_amdgcn_mfma_f32_16x16x32_bf16(AH1[mt], bl1, acc, 0, 0, 0);
      acc = __builtin_amdgcn_mfma_f32_16x16x32_bf16(AL0[mt], bh0, acc, 0, 0, 0);
      acc = __builtin_amdgcn_mfma_f32_16x16x32_bf16(AL1[mt], bh1, acc, 0, 0, 0);
      f32x4 r;
      #pragma unroll
      for (int j = 0; j < 4; ++j) {
        float sq = x2v - 2.0f * acc[j] + C2[mt][j];
        sq = fmaxf(sq, 0.0f);                      // match ref clamp
        r[j] = __builtin_amdgcn_exp2f(-sq * IV[mt][j]);
      }
      // per (row, wave): mt=0..3 -> 4 adjacent 64B chunks = 256B contiguous
      *(f32x4*)(prow + mt * 16) = r;
    }
  }
}

extern "C" void kernel_launch(void* const* d_in, const int* in_sizes, int n_in,
                              void* d_out, int out_size, void* d_ws, size_t ws_size,
                              hipStream_t stream) {
  (void)in_sizes; (void)n_in; (void)out_size; (void)ws_size;
  const float* x       = (const float*)d_in[0];
  const float* centers = (const float*)d_in[1];
  const float* ls      = (const float*)d_in[2];
  float* out = (float*)d_out;

  // ws layout: c_hi (256KB) | c_lo (256KB) | c2 (8KB) | inv2 (8KB)  = 528KB
  char* ws = (char*)d_ws;
  unsigned short* ch = (unsigned short*)(ws);
  unsigned short* cl = (unsigned short*)(ws + 262144);
  float* c2 = (float*)(ws + 524288);
  float* iv = (float*)(ws + 532480);

  rbf_pre<<<OUT_N, 64, 0, stream>>>(centers, ls, ch, cl, c2, iv);
  rbf_main<<<dim3(B_ROWS / ROWS_B, OUT_N / OC_B), 256, 0, stream>>>(x, ch, cl, c2, iv, out);
}